// Round 2
// baseline (214.916 us; speedup 1.0000x reference)
//
#include <hip/hip_runtime.h>

#define THREADS 256
#define WAVE 64
#define GROUPS_PER_BLOCK (THREADS * 2)   // 2 groups of 4 samples per thread

// Fused single-kernel reduction. Each thread handles 8 samples (two groups
// of 4; all 12 vector loads issued before compute). The four loss channels
// are linear in the final result, so weights fold into one per-thread
// scalar -> 6-shuffle wave reduce -> one float partial per block. The last
// block to finish (device-scope ticket) reduces the partials and writes the
// final loss. Reduction order is fixed -> deterministic.
__global__ __launch_bounds__(THREADS) void loss_fused(
    const float4* __restrict__ pred4,   // 2 float4 per group of 4 samples
    const float4* __restrict__ tgt4,
    const float4* __restrict__ prev4,
    const int4*   __restrict__ dt4,
    const int4*   __restrict__ pv4,
    float* __restrict__ partials,
    unsigned int* __restrict__ ticket,
    const float* __restrict__ pred, const float* __restrict__ tgt,
    const float* __restrict__ prev, const int* __restrict__ dt,
    const int* __restrict__ pvv,
    int tail_start, int n, int nblocks, int n4,
    float* __restrict__ out)
{
    int i0 = blockIdx.x * GROUPS_PER_BLOCK + threadIdx.x;
    int i1 = i0 + THREADS;
    bool v0 = (i0 < n4);
    bool v1 = (i1 < n4);

    float4 a0, a1, t0, q0;  int4 d0, e0;
    float4 b0, b1, t1, q1;  int4 d1, e1;

    if (v0) {
        a0 = pred4[2 * i0];
        a1 = pred4[2 * i0 + 1];
        t0 = tgt4[i0];
        q0 = prev4[i0];
        d0 = dt4[i0];
        e0 = pv4[i0];
    }
    if (v1) {
        b0 = pred4[2 * i1];
        b1 = pred4[2 * i1 + 1];
        t1 = tgt4[i1];
        q1 = prev4[i1];
        d1 = dt4[i1];
        e1 = pv4[i1];
    }

    float s0 = 0.f, s1 = 0.f, s2 = 0.f, s3 = 0.f;

    if (v0) {
        float lo[4]  = {a0.x, a0.z, a1.x, a1.z};
        float up[4]  = {a0.y, a0.w, a1.y, a1.w};
        float tga[4] = {t0.x, t0.y, t0.z, t0.w};
        float ppa[4] = {q0.x, q0.y, q0.z, q0.w};
        int   dta[4] = {d0.x, d0.y, d0.z, d0.w};
        int   pva[4] = {e0.x, e0.y, e0.z, e0.w};
#pragma unroll
        for (int j = 0; j < 4; ++j) {
            float c = 0.5f * (lo[j] + up[j]);
            float d = tga[j] - c;
            s0 += d * d;
            s1 += up[j] - lo[j];
            s2 += fmaxf(lo[j] - up[j], 0.0f);
            float diff = c - ppa[j];
            float pen = (pva[j] == 0) ? fmaxf(diff, 0.0f) : fmaxf(-diff, 0.0f);
            s3 += (dta[j] != 0) ? pen : 0.0f;
        }
    }
    if (v1) {
        float lo[4]  = {b0.x, b0.z, b1.x, b1.z};
        float up[4]  = {b0.y, b0.w, b1.y, b1.w};
        float tga[4] = {t1.x, t1.y, t1.z, t1.w};
        float ppa[4] = {q1.x, q1.y, q1.z, q1.w};
        int   dta[4] = {d1.x, d1.y, d1.z, d1.w};
        int   pva[4] = {e1.x, e1.y, e1.z, e1.w};
#pragma unroll
        for (int j = 0; j < 4; ++j) {
            float c = 0.5f * (lo[j] + up[j]);
            float d = tga[j] - c;
            s0 += d * d;
            s1 += up[j] - lo[j];
            s2 += fmaxf(lo[j] - up[j], 0.0f);
            float diff = c - ppa[j];
            float pen = (pva[j] == 0) ? fmaxf(diff, 0.0f) : fmaxf(-diff, 0.0f);
            s3 += (dta[j] != 0) ? pen : 0.0f;
        }
    }

    // Weights are linear -> fold into one scalar before reduction.
    float w = 1.5f * s0 + 0.1f * s1 + 10.0f * s2 + 0.5f * s3;

#pragma unroll
    for (int off = 32; off > 0; off >>= 1)
        w += __shfl_down(w, off, WAVE);

    __shared__ float smem[THREADS / WAVE];
    __shared__ bool is_last;
    if ((threadIdx.x & 63) == 0) smem[threadIdx.x >> 6] = w;
    __syncthreads();
    if (threadIdx.x == 0) {
        float acc = smem[0];
#pragma unroll
        for (int wv = 1; wv < THREADS / WAVE; ++wv) acc += smem[wv];
        partials[blockIdx.x] = acc;
        __threadfence();                         // release: partial visible device-wide
        unsigned int old = atomicAdd(ticket, 1u);
        is_last = (old == (unsigned int)(nblocks - 1));
    }
    __syncthreads();
    if (!is_last) return;

    // ---- last block: final reduction ----
    __threadfence();   // acquire: invalidate L1 (stale lines from prior graph replay)

    float s = 0.f;
    for (int t = threadIdx.x; t < nblocks; t += THREADS)
        s += partials[t];

    if (threadIdx.x == 0) {
        for (int i = tail_start; i < n; ++i) {   // defensive: n % 4 != 0
            float lo = pred[2 * i], up = pred[2 * i + 1];
            float c = 0.5f * (lo + up);
            float d = tgt[i] - c;
            float pen = (pvv[i] == 0) ? fmaxf(c - prev[i], 0.f)
                                      : fmaxf(prev[i] - c, 0.f);
            s += 1.5f * d * d + 0.1f * (up - lo) + 10.0f * fmaxf(lo - up, 0.f)
               + 0.5f * ((dt[i] != 0) ? pen : 0.f);
        }
    }

#pragma unroll
    for (int off = 32; off > 0; off >>= 1)
        s += __shfl_down(s, off, WAVE);

    __syncthreads();   // smem reuse barrier
    if ((threadIdx.x & 63) == 0) smem[threadIdx.x >> 6] = s;
    __syncthreads();
    if (threadIdx.x == 0) {
        float acc = smem[0];
#pragma unroll
        for (int wv = 1; wv < THREADS / WAVE; ++wv) acc += smem[wv];
        out[0] = acc / (float)n;
    }
}

extern "C" void kernel_launch(void* const* d_in, const int* in_sizes, int n_in,
                              void* d_out, int out_size, void* d_ws, size_t ws_size,
                              hipStream_t stream) {
    const float* pred   = (const float*)d_in[0];
    const float* target = (const float*)d_in[1];
    const float* prev   = (const float*)d_in[2];
    const int*   dt     = (const int*)d_in[3];
    const int*   pv     = (const int*)d_in[4];
    float* out = (float*)d_out;

    int n  = in_sizes[3];          // B (delta_time is (B,))
    int n4 = n >> 2;               // groups of 4 samples
    int nblocks = (n4 + GROUPS_PER_BLOCK - 1) / GROUPS_PER_BLOCK;  // 2048

    unsigned int* ticket = (unsigned int*)d_ws;
    float* partials = (float*)((char*)d_ws + 256);   // 2048 * 4 B

    hipMemsetAsync(d_ws, 0, sizeof(unsigned int), stream);  // ticket = 0

    loss_fused<<<nblocks, THREADS, 0, stream>>>(
        (const float4*)pred, (const float4*)target, (const float4*)prev,
        (const int4*)dt, (const int4*)pv, partials, ticket,
        pred, target, prev, dt, pv, n4 * 4, n, nblocks, n4, out);
}

// Round 3
// 121.792 us; speedup vs baseline: 1.7646x; 1.7646x over previous
//
#include <hip/hip_runtime.h>

#define THREADS 256
#define WAVE 64
#define GROUPS 4                                   // float4-groups per thread
#define GROUPS_PER_BLOCK (THREADS * GROUPS)        // 1024 groups = 4096 samples

// Stage 1: each thread handles 16 samples as 4 independent groups of 4.
// All 24 vector loads are issued before any compute (max memory-level
// parallelism). The four loss channels are linear in the final result, so
// weights fold into one per-thread scalar -> 6-shuffle wave reduce -> one
// float partial per block. No device-scope fences/atomics (per-block
// __threadfence on gfx950 = L2 writeback per block = 94 us regression in
// the previous round).
__global__ __launch_bounds__(THREADS) void loss_reduce(
    const float4* __restrict__ pred4,   // 2 float4 per group of 4 samples
    const float4* __restrict__ tgt4,
    const float4* __restrict__ prev4,
    const int4*   __restrict__ dt4,
    const int4*   __restrict__ pv4,
    float* __restrict__ partials,
    int n4)
{
    int base = blockIdx.x * GROUPS_PER_BLOCK + threadIdx.x;

    float4 p0[GROUPS], p1[GROUPS], tg[GROUPS], pp[GROUPS];
    int4   dv[GROUPS], ev[GROUPS];
    bool   vld[GROUPS];

#pragma unroll
    for (int g = 0; g < GROUPS; ++g) {
        int i = base + g * THREADS;
        vld[g] = (i < n4);
        if (vld[g]) {
            p0[g] = pred4[2 * i];
            p1[g] = pred4[2 * i + 1];
            tg[g] = tgt4[i];
            pp[g] = prev4[i];
            dv[g] = dt4[i];
            ev[g] = pv4[i];
        }
    }

    float s0 = 0.f, s1 = 0.f, s2 = 0.f, s3 = 0.f;

#pragma unroll
    for (int g = 0; g < GROUPS; ++g) {
        if (vld[g]) {
            float lo[4]  = {p0[g].x, p0[g].z, p1[g].x, p1[g].z};
            float up[4]  = {p0[g].y, p0[g].w, p1[g].y, p1[g].w};
            float tga[4] = {tg[g].x, tg[g].y, tg[g].z, tg[g].w};
            float ppa[4] = {pp[g].x, pp[g].y, pp[g].z, pp[g].w};
            int   dta[4] = {dv[g].x, dv[g].y, dv[g].z, dv[g].w};
            int   pva[4] = {ev[g].x, ev[g].y, ev[g].z, ev[g].w};
#pragma unroll
            for (int j = 0; j < 4; ++j) {
                float c = 0.5f * (lo[j] + up[j]);
                float d = tga[j] - c;
                s0 += d * d;                       // center_loss
                s1 += up[j] - lo[j];               // width_loss
                s2 += fmaxf(lo[j] - up[j], 0.0f);  // valid_penalty
                float diff = c - ppa[j];
                float pen = (pva[j] == 0) ? fmaxf(diff, 0.0f) : fmaxf(-diff, 0.0f);
                s3 += (dta[j] != 0) ? pen : 0.0f;  // direction_penalty
            }
        }
    }

    // Weights are linear -> fold into one scalar before reduction.
    float w = 1.5f * s0 + 0.1f * s1 + 10.0f * s2 + 0.5f * s3;

#pragma unroll
    for (int off = 32; off > 0; off >>= 1)
        w += __shfl_down(w, off, WAVE);

    __shared__ float smem[THREADS / WAVE];
    if ((threadIdx.x & 63) == 0) smem[threadIdx.x >> 6] = w;
    __syncthreads();
    if (threadIdx.x == 0) {
        float acc = smem[0];
#pragma unroll
        for (int wv = 1; wv < THREADS / WAVE; ++wv) acc += smem[wv];
        partials[blockIdx.x] = acc;
    }
}

// Stage 2: single block combines per-block weighted partials (float4 loads;
// nblocks is a multiple of 4 here) plus a defensive scalar tail, divides by n.
__global__ __launch_bounds__(THREADS) void loss_final(
    const float* __restrict__ partials, int nblocks,
    const float* __restrict__ pred, const float* __restrict__ tgt,
    const float* __restrict__ prev, const int* __restrict__ dt,
    const int* __restrict__ pvv,
    int tail_start, int n,
    float* __restrict__ out)
{
    float s = 0.f;
    int nb4 = nblocks >> 2;
    const float4* partials4 = (const float4*)partials;
    for (int t = threadIdx.x; t < nb4; t += THREADS) {
        float4 p = partials4[t];
        s += p.x + p.y + p.z + p.w;
    }
    if (threadIdx.x == 0) {
        for (int t = nb4 << 2; t < nblocks; ++t) s += partials[t];
        for (int i = tail_start; i < n; ++i) {   // defensive: n % 4 != 0
            float lo = pred[2 * i], up = pred[2 * i + 1];
            float c = 0.5f * (lo + up);
            float d = tgt[i] - c;
            float pen = (pvv[i] == 0) ? fmaxf(c - prev[i], 0.f)
                                      : fmaxf(prev[i] - c, 0.f);
            s += 1.5f * d * d + 0.1f * (up - lo) + 10.0f * fmaxf(lo - up, 0.f)
               + 0.5f * ((dt[i] != 0) ? pen : 0.f);
        }
    }

#pragma unroll
    for (int off = 32; off > 0; off >>= 1)
        s += __shfl_down(s, off, WAVE);

    __shared__ float smem[THREADS / WAVE];
    if ((threadIdx.x & 63) == 0) smem[threadIdx.x >> 6] = s;
    __syncthreads();
    if (threadIdx.x == 0) {
        float acc = smem[0];
#pragma unroll
        for (int wv = 1; wv < THREADS / WAVE; ++wv) acc += smem[wv];
        out[0] = acc / (float)n;
    }
}

extern "C" void kernel_launch(void* const* d_in, const int* in_sizes, int n_in,
                              void* d_out, int out_size, void* d_ws, size_t ws_size,
                              hipStream_t stream) {
    const float* pred   = (const float*)d_in[0];
    const float* target = (const float*)d_in[1];
    const float* prev   = (const float*)d_in[2];
    const int*   dt     = (const int*)d_in[3];
    const int*   pv     = (const int*)d_in[4];
    float* out = (float*)d_out;

    int n  = in_sizes[3];          // B (delta_time is (B,))
    int n4 = n >> 2;               // groups of 4 samples
    int nblocks = (n4 + GROUPS_PER_BLOCK - 1) / GROUPS_PER_BLOCK;  // 1024

    float* partials = (float*)d_ws;   // 1024 * 4 B = 4 KB

    loss_reduce<<<nblocks, THREADS, 0, stream>>>(
        (const float4*)pred, (const float4*)target, (const float4*)prev,
        (const int4*)dt, (const int4*)pv, partials, n4);

    loss_final<<<1, THREADS, 0, stream>>>(
        partials, nblocks, pred, target, prev, dt, pv, n4 * 4, n, out);
}